// Round 5
// baseline (586.531 us; speedup 1.0000x reference)
//
#include <hip/hip_runtime.h>

typedef __bf16 bf16x8 __attribute__((ext_vector_type(8)));
typedef float f32x4 __attribute__((ext_vector_type(4)));
typedef ushort u16x8 __attribute__((ext_vector_type(8)));

__device__ __forceinline__ float bf2f(ushort u) {
    union { unsigned int i; float f; } v; v.i = ((unsigned int)u) << 16; return v.f;
}
__device__ __forceinline__ ushort f2bf(float f) {
    union { float f; unsigned int i; } v; v.f = f;
    unsigned int i = v.i;
    return (ushort)((i + 0x7FFFu + ((i >> 16) & 1u)) >> 16);  // RNE
}
__device__ __forceinline__ unsigned int addmul_bf2(unsigned int xs, unsigned int es, float sc) {
    float f0 = bf2f((ushort)(xs & 0xffffu)) + sc * bf2f((ushort)(es & 0xffffu));
    float f1 = bf2f((ushort)(xs >> 16))     + sc * bf2f((ushort)(es >> 16));
    return (unsigned int)f2bf(f0) | (((unsigned int)f2bf(f1)) << 16);
}

// ---------------------------------------------------------------------------
// Kernel 0: dtype sniffer. flag=1 -> float inputs are f32.
// ---------------------------------------------------------------------------
__global__ __launch_bounds__(256) void sniff_kernel(
    const unsigned int* __restrict__ bs_words, int* __restrict__ flag)
{
    const int t = threadIdx.x;
    int hit = 0;
    for (int i = 0; i < 64; ++i) {
        unsigned int w = bs_words[t * 64 + i];
        unsigned int e0 = (w >> 7)  & 0xffu;
        unsigned int e1 = (w >> 23) & 0xffu;
        if (e0 > 150u || e1 > 150u) hit = 1;
    }
    __shared__ int s;
    if (t == 0) s = 0;
    __syncthreads();
    if (hit) atomicOr(&s, 1);
    __syncthreads();
    if (t == 0) *flag = s;
}

// ---------------------------------------------------------------------------
// Kernel 1: blocks 0..255: weight transpose -> Wqkv_t[768][256], Wo_t[256][256]
// (bf16 [n][k]). Block 256: classify the five 256-elem candidates (img_ids =
// nonzero words, all <32; biases are exact zeros), rank/gsize, biases -> f32.
// ---------------------------------------------------------------------------
__global__ __launch_bounds__(256) void prep_kernel(
    const int* __restrict__ flag,
    const void* __restrict__ Wq, const void* __restrict__ Wk,
    const void* __restrict__ Wv, const void* __restrict__ Wo,
    const void* __restrict__ c0, const void* __restrict__ c1,
    const void* __restrict__ c2, const void* __restrict__ c3,
    const void* __restrict__ c4, const void* __restrict__ scale_in,
    int* __restrict__ rank, int* __restrict__ gsize,
    ushort* __restrict__ Wqkv_t, ushort* __restrict__ Wo_t,
    float* __restrict__ bqkv_f, float* __restrict__ bo_f,
    float* __restrict__ scale_f)
{
    const int blk = blockIdx.x;
    const int t = threadIdx.x;
    const bool is_f32 = (*flag != 0);
    if (blk < 256) {
        const int k = blk;
        ushort q, kk, vv, oo;
        if (is_f32) {
            q  = f2bf(((const float*)Wq)[k * 256 + t]);
            kk = f2bf(((const float*)Wk)[k * 256 + t]);
            vv = f2bf(((const float*)Wv)[k * 256 + t]);
            oo = f2bf(((const float*)Wo)[k * 256 + t]);
        } else {
            q  = ((const ushort*)Wq)[k * 256 + t];
            kk = ((const ushort*)Wk)[k * 256 + t];
            vv = ((const ushort*)Wv)[k * 256 + t];
            oo = ((const ushort*)Wo)[k * 256 + t];
        }
        Wqkv_t[(size_t)t * 256 + k]         = q;
        Wqkv_t[(size_t)(256 + t) * 256 + k] = kk;
        Wqkv_t[(size_t)(512 + t) * 256 + k] = vv;
        Wo_t[(size_t)t * 256 + k]           = oo;
    } else {
        const void* cands[5] = {c0, c1, c2, c3, c4};
        __shared__ int cstat[5];
        if (t < 5) cstat[t] = 0;
        __syncthreads();
        #pragma unroll
        for (int c = 0; c < 5; ++c) {
            unsigned int wv = ((const unsigned int*)cands[c])[t];
            int fl = ((wv != 0u) ? 1 : 0) | ((wv >= 32u) ? 2 : 0);
            if (fl) atomicOr(&cstat[c], fl);
        }
        __syncthreads();
        int sel = 0;
        #pragma unroll
        for (int c = 4; c >= 0; --c)
            if (cstat[c] == 1) sel = c;
        const int* ids = (const int*)cands[sel];
        int bp[4];
        { int n = 0;
          #pragma unroll
          for (int c = 0; c < 5; ++c) if (c != sel) bp[n++] = c; }

        const int b = t;
        const int my = ids[b];
        int r = 0, g = 0;
        for (int j = 0; j < 256; ++j) {
            bool same = (ids[j] == my);
            r += (same && (j < b)) ? 1 : 0;
            g += same ? 1 : 0;
        }
        rank[b]  = (r > 49) ? 49 : r;
        gsize[b] = g;

        float vq, vk, vv2, vo2;
        if (is_f32) {
            vq  = ((const float*)cands[bp[0]])[t];
            vk  = ((const float*)cands[bp[1]])[t];
            vv2 = ((const float*)cands[bp[2]])[t];
            vo2 = ((const float*)cands[bp[3]])[t];
            if (t == 0) *scale_f = ((const float*)scale_in)[0];
        } else {
            vq  = bf2f(((const ushort*)cands[bp[0]])[t]);
            vk  = bf2f(((const ushort*)cands[bp[1]])[t]);
            vv2 = bf2f(((const ushort*)cands[bp[2]])[t]);
            vo2 = bf2f(((const ushort*)cands[bp[3]])[t]);
            if (t == 0) *scale_f = bf2f(((const ushort*)scale_in)[0]);
        }
        bqkv_f[t]       = vq;
        bqkv_f[256 + t] = vk;
        bqkv_f[512 + t] = vv2;
        bo_f[t]         = vo2;
    }
}

// ---------------------------------------------------------------------------
// Kernel 2: FUSED per-(b,h): Q projection (4 m-blocks, Qtmp handoff via Kl),
// then per-64-key-chunk: K/V projection -> LDS, flash attention update.
// LDS = 62 KB. ctx (bf16) written to ws.
// ---------------------------------------------------------------------------
__global__ __launch_bounds__(256, 1) void fused_attn_kernel(
    const int* __restrict__ flag,
    const void* __restrict__ bs, const void* __restrict__ obj_emb,
    const float* __restrict__ scale_f, const ushort* __restrict__ Wqkv_t,
    const float* __restrict__ bqkv_f, const int* __restrict__ rank,
    ushort* __restrict__ ctx)
{
    __shared__ __attribute__((aligned(16))) ushort As[2][64 * 32];  // 8 KB
    __shared__ __attribute__((aligned(16))) ushort Kl[64 * 72];     // 9 KB (Qtmp)
    __shared__ __attribute__((aligned(16))) ushort Vl[64 * 72];     // 9 KB
    __shared__ __attribute__((aligned(16))) ushort Pl[4][64 * 72];  // 36 KB

    const int bh = blockIdx.x;
    const int b = bh >> 2, h = bh & 3;
    const int tid = threadIdx.x;
    const int w = tid >> 6, l = tid & 63, quad = l >> 4, l15 = l & 15;
    const bool is_f32 = (*flag != 0);
    const float sc = *scale_f;
    const int rk = rank[b];

    auto stageA = [&](int buf, int r0, int k0) {
        const int row = tid >> 2, c8 = (tid & 3) * 8;
        const size_t off = ((size_t)(b * 256 + r0 + row)) * 256 + k0 + c8;
        if (is_f32) {
            const float* bsf = (const float*)bs;
            const float* ef  = (const float*)obj_emb + rk * 256 + k0 + c8;
            float4 x0 = *(const float4*)(bsf + off);
            float4 x1 = *(const float4*)(bsf + off + 4);
            float4 e0 = *(const float4*)(ef);
            float4 e1 = *(const float4*)(ef + 4);
            u16x8 o;
            o[0] = f2bf(x0.x + sc * e0.x); o[1] = f2bf(x0.y + sc * e0.y);
            o[2] = f2bf(x0.z + sc * e0.z); o[3] = f2bf(x0.w + sc * e0.w);
            o[4] = f2bf(x1.x + sc * e1.x); o[5] = f2bf(x1.y + sc * e1.y);
            o[6] = f2bf(x1.z + sc * e1.z); o[7] = f2bf(x1.w + sc * e1.w);
            *(u16x8*)&As[buf][row * 32 + c8] = o;
        } else {
            const ushort* b16 = (const ushort*)bs;
            const ushort* ef  = (const ushort*)obj_emb + rk * 256 + k0 + c8;
            uint4 x = *(const uint4*)(b16 + off);
            uint4 e = *(const uint4*)ef;
            uint4 o;
            o.x = addmul_bf2(x.x, e.x, sc);
            o.y = addmul_bf2(x.y, e.y, sc);
            o.z = addmul_bf2(x.z, e.z, sc);
            o.w = addmul_bf2(x.w, e.w, sc);
            *(uint4*)&As[buf][row * 32 + c8] = o;
        }
    };

    // ===== Q phase =====
    bf16x8 qf[4][2];
    for (int j = 0; j < 4; ++j) {
        f32x4 qa[4];
        #pragma unroll
        for (int nt = 0; nt < 4; ++nt) { f32x4 z = {0.f,0.f,0.f,0.f}; qa[nt] = z; }
        for (int k0 = 0; k0 < 256; k0 += 32) {
            const int buf = (k0 >> 5) & 1;
            stageA(buf, j * 64, k0);
            bf16x8 a = *(const bf16x8*)&As[buf][(w * 16 + l15) * 32 + quad * 8];
            #pragma unroll
            for (int nt = 0; nt < 4; ++nt) {
                bf16x8 bb = *(const bf16x8*)(Wqkv_t +
                    (size_t)(h * 64 + nt * 16 + l15) * 256 + k0 + quad * 8);
                qa[nt] = __builtin_amdgcn_mfma_f32_16x16x32_bf16(a, bb, qa[nt], 0, 0, 0);
            }
        }
        #pragma unroll
        for (int nt = 0; nt < 4; ++nt) {
            const float bias = bqkv_f[h * 64 + nt * 16 + l15];
            #pragma unroll
            for (int r = 0; r < 4; ++r)
                Kl[(w * 16 + quad * 4 + r) * 72 + nt * 16 + l15] =
                    f2bf((qa[nt][r] + bias) * 0.125f);
        }
        __syncthreads();
        if (w == j) {
            #pragma unroll
            for (int mt = 0; mt < 4; ++mt)
                #pragma unroll
                for (int ks = 0; ks < 2; ++ks)
                    qf[mt][ks] = *(const bf16x8*)&Kl[(mt * 16 + l15) * 72 +
                                                     ks * 32 + quad * 8];
        }
        __syncthreads();
    }

    // ===== flash attention over 4 key-chunks =====
    f32x4 O[4][4];
    float m_run[4][4], l_run[4][4];
    #pragma unroll
    for (int mt = 0; mt < 4; ++mt) {
        #pragma unroll
        for (int dt = 0; dt < 4; ++dt) { f32x4 z = {0.f,0.f,0.f,0.f}; O[mt][dt] = z; }
        #pragma unroll
        for (int r = 0; r < 4; ++r) { m_run[mt][r] = -1e30f; l_run[mt][r] = 0.f; }
    }

    for (int c = 0; c < 4; ++c) {
        f32x4 kv[8];
        #pragma unroll
        for (int nt = 0; nt < 8; ++nt) { f32x4 z = {0.f,0.f,0.f,0.f}; kv[nt] = z; }
        for (int k0 = 0; k0 < 256; k0 += 32) {
            const int buf = (k0 >> 5) & 1;
            stageA(buf, c * 64, k0);
            bf16x8 a = *(const bf16x8*)&As[buf][(w * 16 + l15) * 32 + quad * 8];
            #pragma unroll
            for (int nt = 0; nt < 8; ++nt) {
                const int ng = (nt < 4) ? (256 + h * 64 + nt * 16 + l15)
                                        : (512 + h * 64 + (nt - 4) * 16 + l15);
                bf16x8 bb = *(const bf16x8*)(Wqkv_t + (size_t)ng * 256 + k0 + quad * 8);
                kv[nt] = __builtin_amdgcn_mfma_f32_16x16x32_bf16(a, bb, kv[nt], 0, 0, 0);
            }
        }
        #pragma unroll
        for (int nt = 0; nt < 8; ++nt) {
            if (nt < 4) {
                const int d = nt * 16 + l15;
                const float bias = bqkv_f[256 + h * 64 + d];
                #pragma unroll
                for (int r = 0; r < 4; ++r)
                    Kl[(w * 16 + quad * 4 + r) * 72 + d] = f2bf(kv[nt][r] + bias);
            } else {
                const int d = (nt - 4) * 16 + l15;
                const float bias = bqkv_f[512 + h * 64 + d];
                #pragma unroll
                for (int r = 0; r < 4; ++r)
                    Vl[d * 72 + (w * 16 + quad * 4 + r)] = f2bf(kv[nt][r] + bias);
            }
        }
        __syncthreads();

        f32x4 sacc[4][4];
        #pragma unroll
        for (int mt = 0; mt < 4; ++mt)
            #pragma unroll
            for (int nt = 0; nt < 4; ++nt) { f32x4 z = {0.f,0.f,0.f,0.f}; sacc[mt][nt] = z; }
        #pragma unroll
        for (int ks = 0; ks < 2; ++ks) {
            bf16x8 kf[4];
            #pragma unroll
            for (int nt = 0; nt < 4; ++nt)
                kf[nt] = *(const bf16x8*)&Kl[(nt * 16 + l15) * 72 + ks * 32 + quad * 8];
            #pragma unroll
            for (int mt = 0; mt < 4; ++mt)
                #pragma unroll
                for (int nt = 0; nt < 4; ++nt)
                    sacc[mt][nt] = __builtin_amdgcn_mfma_f32_16x16x32_bf16(
                        qf[mt][ks], kf[nt], sacc[mt][nt], 0, 0, 0);
        }

        #pragma unroll
        for (int mt = 0; mt < 4; ++mt) {
            f32x4 mx = sacc[mt][0];
            #pragma unroll
            for (int nt = 1; nt < 4; ++nt)
                #pragma unroll
                for (int r = 0; r < 4; ++r) mx[r] = fmaxf(mx[r], sacc[mt][nt][r]);
            #pragma unroll
            for (int r = 0; r < 4; ++r) {
                float v = mx[r];
                v = fmaxf(v, __shfl_xor(v, 1));
                v = fmaxf(v, __shfl_xor(v, 2));
                v = fmaxf(v, __shfl_xor(v, 4));
                v = fmaxf(v, __shfl_xor(v, 8));
                mx[r] = v;
            }
            float rs[4];
            #pragma unroll
            for (int r = 0; r < 4; ++r) {
                float nm = fmaxf(m_run[mt][r], mx[r]);
                float alpha = __expf(m_run[mt][r] - nm);
                m_run[mt][r] = nm;
                l_run[mt][r] *= alpha;
                float sum = 0.f;
                #pragma unroll
                for (int nt = 0; nt < 4; ++nt) {
                    float p = __expf(sacc[mt][nt][r] - nm);
                    sacc[mt][nt][r] = p;
                    sum += p;
                }
                rs[r] = sum;
                #pragma unroll
                for (int dt = 0; dt < 4; ++dt) O[mt][dt][r] *= alpha;
            }
            #pragma unroll
            for (int r = 0; r < 4; ++r) {
                float v = rs[r];
                v += __shfl_xor(v, 1);
                v += __shfl_xor(v, 2);
                v += __shfl_xor(v, 4);
                v += __shfl_xor(v, 8);
                l_run[mt][r] += v;
            }
            #pragma unroll
            for (int nt = 0; nt < 4; ++nt)
                #pragma unroll
                for (int r = 0; r < 4; ++r)
                    Pl[w][(mt * 16 + quad * 4 + r) * 72 + nt * 16 + l15] =
                        f2bf(sacc[mt][nt][r]);
        }

        #pragma unroll
        for (int ks = 0; ks < 2; ++ks) {
            bf16x8 pf[4], vf[4];
            #pragma unroll
            for (int mt = 0; mt < 4; ++mt)
                pf[mt] = *(const bf16x8*)&Pl[w][(mt * 16 + l15) * 72 + ks * 32 + quad * 8];
            #pragma unroll
            for (int dt = 0; dt < 4; ++dt)
                vf[dt] = *(const bf16x8*)&Vl[(dt * 16 + l15) * 72 + ks * 32 + quad * 8];
            #pragma unroll
            for (int mt = 0; mt < 4; ++mt)
                #pragma unroll
                for (int dt = 0; dt < 4; ++dt)
                    O[mt][dt] = __builtin_amdgcn_mfma_f32_16x16x32_bf16(
                        pf[mt], vf[dt], O[mt][dt], 0, 0, 0);
        }
        __syncthreads();
    }

    #pragma unroll
    for (int mt = 0; mt < 4; ++mt) {
        #pragma unroll
        for (int r = 0; r < 4; ++r) {
            float inv = 1.0f / l_run[mt][r];
            const int s = w * 64 + mt * 16 + quad * 4 + r;
            const size_t base = ((size_t)(b * 256 + s)) * 256 + h * 64;
            #pragma unroll
            for (int dt = 0; dt < 4; ++dt)
                ctx[base + dt * 16 + l15] = f2bf(O[mt][dt][r] * inv);
        }
    }
}

// ---------------------------------------------------------------------------
// Kernel 3: out = gsize>1 ? bs + ctx@Wo + bo : bs.
// OUTPUT DTYPE MATCHES INPUT DTYPE: f32 store when flag=1, bf16 otherwise.
// ---------------------------------------------------------------------------
__global__ __launch_bounds__(256) void out_kernel(
    const int* __restrict__ flag,
    const ushort* __restrict__ ctx, const ushort* __restrict__ Wo_t,
    const float* __restrict__ bo_f, const void* __restrict__ bs,
    const int* __restrict__ gsize, void* __restrict__ outv)
{
    __shared__ __attribute__((aligned(16))) ushort A_lds[64 * 32];
    __shared__ __attribute__((aligned(16))) ushort B_lds[256 * 32];

    const int m0 = blockIdx.x * 64;
    const int tid = threadIdx.x;
    const int w = tid >> 6, l = tid & 63, quad = l >> 4, l15 = l & 15;
    const int b = m0 >> 8;
    const bool pass = (gsize[b] <= 1);
    const bool is_f32 = (*flag != 0);

    f32x4 acc[4][4];
    #pragma unroll
    for (int i = 0; i < 4; ++i)
        #pragma unroll
        for (int j = 0; j < 4; ++j) { f32x4 z = {0.f,0.f,0.f,0.f}; acc[i][j] = z; }

    const int arow = tid >> 2, ako = (tid & 3) * 8;
    for (int k0 = 0; k0 < 256; k0 += 32) {
        *(uint4*)&A_lds[arow * 32 + ako] =
            *(const uint4*)(ctx + (((size_t)(m0 + arow)) << 8) + k0 + ako);
        #pragma unroll
        for (int i = 0; i < 4; ++i) {
            int f = tid + i * 256;
            int n = f >> 2, ko = (f & 3) * 8;
            *(uint4*)&B_lds[n * 32 + ko] =
                *(const uint4*)(Wo_t + (((size_t)n) << 8) + k0 + ko);
        }
        __syncthreads();
        bf16x8 a[4], bb[4];
        #pragma unroll
        for (int mt = 0; mt < 4; ++mt)
            a[mt] = *(const bf16x8*)&A_lds[(mt * 16 + l15) * 32 + quad * 8];
        #pragma unroll
        for (int nt = 0; nt < 4; ++nt)
            bb[nt] = *(const bf16x8*)&B_lds[(w * 64 + nt * 16 + l15) * 32 + quad * 8];
        #pragma unroll
        for (int mt = 0; mt < 4; ++mt)
            #pragma unroll
            for (int nt = 0; nt < 4; ++nt)
                acc[mt][nt] = __builtin_amdgcn_mfma_f32_16x16x32_bf16(
                    a[mt], bb[nt], acc[mt][nt], 0, 0, 0);
        __syncthreads();
    }

    #pragma unroll
    for (int nt = 0; nt < 4; ++nt) {
        const int n = w * 64 + nt * 16 + l15;
        const float bias = bo_f[n];
        #pragma unroll
        for (int mt = 0; mt < 4; ++mt)
            #pragma unroll
            for (int r = 0; r < 4; ++r) {
                int token = m0 + mt * 16 + quad * 4 + r;
                size_t idx = (((size_t)token) << 8) + n;
                float base = is_f32 ? ((const float*)bs)[idx]
                                    : bf2f(((const ushort*)bs)[idx]);
                float v = pass ? base : (base + acc[mt][nt][r] + bias);
                if (is_f32) ((float*)outv)[idx] = v;
                else        ((ushort*)outv)[idx] = f2bf(v);
            }
    }
}

// ---------------------------------------------------------------------------
extern "C" void kernel_launch(void* const* d_in, const int* in_sizes, int n_in,
                              void* d_out, int out_size, void* d_ws, size_t ws_size,
                              hipStream_t stream)
{
    int bs_i = -1, obj_i = -1, sc_i = -1;
    int w_i[4] = {2, 3, 4, 5}; int nw = 0;
    int c_i[5] = {1, 6, 7, 8, 9}; int nc = 0;
    for (int i = 0; i < n_in; ++i) {
        int s = in_sizes[i];
        if      (s == 16777216) bs_i = i;
        else if (s == 65536)  { if (nw < 4) w_i[nw] = i; ++nw; }
        else if (s == 12800)    obj_i = i;
        else if (s == 1)        sc_i = i;
        else if (s == 256)    { if (nc < 5) c_i[nc] = i; ++nc; }
    }
    if (bs_i < 0 || obj_i < 0 || sc_i < 0 || nw != 4 || nc != 5) {
        bs_i = 0; obj_i = 10; sc_i = 11;
        w_i[0] = 2; w_i[1] = 3; w_i[2] = 4; w_i[3] = 5;
        c_i[0] = 1; c_i[1] = 6; c_i[2] = 7; c_i[3] = 8; c_i[4] = 9;
    }
    const void* bs    = d_in[bs_i];
    const void* Wq    = d_in[w_i[0]];
    const void* Wk    = d_in[w_i[1]];
    const void* Wv    = d_in[w_i[2]];
    const void* Wo    = d_in[w_i[3]];
    const void* obj   = d_in[obj_i];
    const void* scale = d_in[sc_i];

    char* ws = (char*)d_ws;
    int*    flag    = (int*)ws;
    int*    rank    = (int*)(ws + 1024);
    int*    gsize   = (int*)(ws + 2048);
    float*  scale_f = (float*)(ws + 3072);
    float*  bqkv_f  = (float*)(ws + 4096);
    float*  bo_f    = (float*)(ws + 8192);
    ushort* Wqkv_t  = (ushort*)(ws + 16384);
    ushort* Wo_t    = (ushort*)(ws + 16384 + 393216);
    ushort* ctx     = (ushort*)(ws + (1 << 20));      // 33.5 MB bf16 scratch

    hipLaunchKernelGGL(sniff_kernel, dim3(1), dim3(256), 0, stream,
                       (const unsigned int*)bs, flag);
    hipLaunchKernelGGL(prep_kernel, dim3(257), dim3(256), 0, stream,
                       flag, Wq, Wk, Wv, Wo,
                       d_in[c_i[0]], d_in[c_i[1]], d_in[c_i[2]],
                       d_in[c_i[3]], d_in[c_i[4]], scale,
                       rank, gsize, Wqkv_t, Wo_t, bqkv_f, bo_f, scale_f);
    hipLaunchKernelGGL(fused_attn_kernel, dim3(1024), dim3(256), 0, stream,
                       flag, bs, obj, scale_f, Wqkv_t, bqkv_f, rank, ctx);
    hipLaunchKernelGGL(out_kernel, dim3(1024), dim3(256), 0, stream,
                       flag, ctx, Wo_t, bo_f, bs, gsize, d_out);
}

// Round 6
// 334.638 us; speedup vs baseline: 1.7527x; 1.7527x over previous
//
#include <hip/hip_runtime.h>

typedef __bf16 bf16x8 __attribute__((ext_vector_type(8)));
typedef float f32x4 __attribute__((ext_vector_type(4)));
typedef ushort u16x8 __attribute__((ext_vector_type(8)));

__device__ __forceinline__ float bf2f(ushort u) {
    union { unsigned int i; float f; } v; v.i = ((unsigned int)u) << 16; return v.f;
}
__device__ __forceinline__ ushort f2bf(float f) {
    union { float f; unsigned int i; } v; v.f = f;
    unsigned int i = v.i;
    return (ushort)((i + 0x7FFFu + ((i >> 16) & 1u)) >> 16);  // RNE
}
__device__ __forceinline__ unsigned int addmul_bf2(unsigned int xs, unsigned int es, float sc) {
    float f0 = bf2f((ushort)(xs & 0xffffu)) + sc * bf2f((ushort)(es & 0xffffu));
    float f1 = bf2f((ushort)(xs >> 16))     + sc * bf2f((ushort)(es >> 16));
    return (unsigned int)f2bf(f0) | (((unsigned int)f2bf(f1)) << 16);
}

// ---------------------------------------------------------------------------
// Kernel 0: dtype sniffer. flag=1 -> float inputs are f32.
// ---------------------------------------------------------------------------
__global__ __launch_bounds__(256) void sniff_kernel(
    const unsigned int* __restrict__ bs_words, int* __restrict__ flag)
{
    const int t = threadIdx.x;
    int hit = 0;
    for (int i = 0; i < 64; ++i) {
        unsigned int w = bs_words[t * 64 + i];
        unsigned int e0 = (w >> 7)  & 0xffu;
        unsigned int e1 = (w >> 23) & 0xffu;
        if (e0 > 150u || e1 > 150u) hit = 1;
    }
    __shared__ int s;
    if (t == 0) s = 0;
    __syncthreads();
    if (hit) atomicOr(&s, 1);
    __syncthreads();
    if (t == 0) *flag = s;
}

// ---------------------------------------------------------------------------
// Kernel 1: blocks 0..255: weight transpose -> Wqkv_t[768][256], Wo_t[256][256]
// (bf16 [n][k]). Block 256: classify five 256-elem candidates (img_ids =
// nonzero words, all <32; biases exact zeros), rank/gsize, biases -> f32.
// ---------------------------------------------------------------------------
__global__ __launch_bounds__(256) void prep_kernel(
    const int* __restrict__ flag,
    const void* __restrict__ Wq, const void* __restrict__ Wk,
    const void* __restrict__ Wv, const void* __restrict__ Wo,
    const void* __restrict__ c0, const void* __restrict__ c1,
    const void* __restrict__ c2, const void* __restrict__ c3,
    const void* __restrict__ c4, const void* __restrict__ scale_in,
    int* __restrict__ rank, int* __restrict__ gsize,
    ushort* __restrict__ Wqkv_t, ushort* __restrict__ Wo_t,
    float* __restrict__ bqkv_f, float* __restrict__ bo_f,
    float* __restrict__ scale_f)
{
    const int blk = blockIdx.x;
    const int t = threadIdx.x;
    const bool is_f32 = (*flag != 0);
    if (blk < 256) {
        const int k = blk;
        ushort q, kk, vv, oo;
        if (is_f32) {
            q  = f2bf(((const float*)Wq)[k * 256 + t]);
            kk = f2bf(((const float*)Wk)[k * 256 + t]);
            vv = f2bf(((const float*)Wv)[k * 256 + t]);
            oo = f2bf(((const float*)Wo)[k * 256 + t]);
        } else {
            q  = ((const ushort*)Wq)[k * 256 + t];
            kk = ((const ushort*)Wk)[k * 256 + t];
            vv = ((const ushort*)Wv)[k * 256 + t];
            oo = ((const ushort*)Wo)[k * 256 + t];
        }
        Wqkv_t[(size_t)t * 256 + k]         = q;
        Wqkv_t[(size_t)(256 + t) * 256 + k] = kk;
        Wqkv_t[(size_t)(512 + t) * 256 + k] = vv;
        Wo_t[(size_t)t * 256 + k]           = oo;
    } else {
        const void* cands[5] = {c0, c1, c2, c3, c4};
        __shared__ int cstat[5];
        if (t < 5) cstat[t] = 0;
        __syncthreads();
        #pragma unroll
        for (int c = 0; c < 5; ++c) {
            unsigned int wv = ((const unsigned int*)cands[c])[t];
            int fl = ((wv != 0u) ? 1 : 0) | ((wv >= 32u) ? 2 : 0);
            if (fl) atomicOr(&cstat[c], fl);
        }
        __syncthreads();
        int sel = 0;
        #pragma unroll
        for (int c = 4; c >= 0; --c)
            if (cstat[c] == 1) sel = c;
        const int* ids = (const int*)cands[sel];
        int bp[4];
        { int n = 0;
          #pragma unroll
          for (int c = 0; c < 5; ++c) if (c != sel) bp[n++] = c; }

        const int b = t;
        const int my = ids[b];
        int r = 0, g = 0;
        for (int j = 0; j < 256; ++j) {
            bool same = (ids[j] == my);
            r += (same && (j < b)) ? 1 : 0;
            g += same ? 1 : 0;
        }
        rank[b]  = (r > 49) ? 49 : r;
        gsize[b] = g;

        float vq, vk, vv2, vo2;
        if (is_f32) {
            vq  = ((const float*)cands[bp[0]])[t];
            vk  = ((const float*)cands[bp[1]])[t];
            vv2 = ((const float*)cands[bp[2]])[t];
            vo2 = ((const float*)cands[bp[3]])[t];
            if (t == 0) *scale_f = ((const float*)scale_in)[0];
        } else {
            vq  = bf2f(((const ushort*)cands[bp[0]])[t]);
            vk  = bf2f(((const ushort*)cands[bp[1]])[t]);
            vv2 = bf2f(((const ushort*)cands[bp[2]])[t]);
            vo2 = bf2f(((const ushort*)cands[bp[3]])[t]);
            if (t == 0) *scale_f = bf2f(((const ushort*)scale_in)[0]);
        }
        bqkv_f[t]       = vq;
        bqkv_f[256 + t] = vk;
        bqkv_f[512 + t] = vv2;
        bo_f[t]         = vo2;
    }
}

// ---------------------------------------------------------------------------
// Kernel 2: QKV projection GEMM for one half of the batches (128 batches =
// 32768 token rows). Grid (3, 512): n-block of 256 cols (seg Q/K/V), m-block
// of 64 tokens. enh computed on the fly while staging A. Outputs into d_out
// scratch: Q,K [bh_l][s][64] (Q has bias & 1/8 folded), Vt [bh_l][64][s].
// ---------------------------------------------------------------------------
__global__ __launch_bounds__(256, 2) void qkv_half_kernel(
    const int* __restrict__ flag,
    const void* __restrict__ bs, const void* __restrict__ obj_emb,
    const float* __restrict__ scale_f, const ushort* __restrict__ Wqkv_t,
    const float* __restrict__ bqkv_f, const int* __restrict__ rank,
    int half,
    ushort* __restrict__ Qg, ushort* __restrict__ Kg, ushort* __restrict__ Vt)
{
    __shared__ __attribute__((aligned(16))) ushort A_lds[64 * 32];
    __shared__ __attribute__((aligned(16))) ushort B_lds[256 * 32];

    const int m0 = half * 32768 + blockIdx.y * 64;   // global token row
    const int n0 = blockIdx.x * 256;
    const int b  = m0 >> 8;          // global batch
    const int bl = b & 127;          // batch within half
    const int tid = threadIdx.x;
    const int w = tid >> 6, l = tid & 63, quad = l >> 4, l15 = l & 15;
    const bool is_f32 = (*flag != 0);
    const float sc = *scale_f;
    const int rk = rank[b];

    f32x4 acc[4][4];
    #pragma unroll
    for (int i = 0; i < 4; ++i)
        #pragma unroll
        for (int j = 0; j < 4; ++j) { f32x4 z = {0.f,0.f,0.f,0.f}; acc[i][j] = z; }

    const int arow = tid >> 2, ako = (tid & 3) * 8;

    for (int k0 = 0; k0 < 256; k0 += 32) {
        // stage A: enh[m0..m0+63][k0..k0+31]
        const size_t aoff = (((size_t)(m0 + arow)) << 8) + k0 + ako;
        if (is_f32) {
            const float* bsf = (const float*)bs;
            const float* ef  = (const float*)obj_emb + rk * 256 + k0 + ako;
            float4 x0 = *(const float4*)(bsf + aoff);
            float4 x1 = *(const float4*)(bsf + aoff + 4);
            float4 e0 = *(const float4*)(ef);
            float4 e1 = *(const float4*)(ef + 4);
            u16x8 o;
            o[0] = f2bf(x0.x + sc * e0.x); o[1] = f2bf(x0.y + sc * e0.y);
            o[2] = f2bf(x0.z + sc * e0.z); o[3] = f2bf(x0.w + sc * e0.w);
            o[4] = f2bf(x1.x + sc * e1.x); o[5] = f2bf(x1.y + sc * e1.y);
            o[6] = f2bf(x1.z + sc * e1.z); o[7] = f2bf(x1.w + sc * e1.w);
            *(u16x8*)&A_lds[arow * 32 + ako] = o;
        } else {
            const ushort* b16 = (const ushort*)bs;
            const ushort* ef  = (const ushort*)obj_emb + rk * 256 + k0 + ako;
            uint4 x = *(const uint4*)(b16 + aoff);
            uint4 e = *(const uint4*)ef;
            uint4 o;
            o.x = addmul_bf2(x.x, e.x, sc);
            o.y = addmul_bf2(x.y, e.y, sc);
            o.z = addmul_bf2(x.z, e.z, sc);
            o.w = addmul_bf2(x.w, e.w, sc);
            *(uint4*)&A_lds[arow * 32 + ako] = o;
        }
        // stage B: Wqkv_t[n0+n][k0..k0+31]
        #pragma unroll
        for (int i = 0; i < 4; ++i) {
            int f = tid + i * 256;
            int n = f >> 2, ko = (f & 3) * 8;
            *(uint4*)&B_lds[n * 32 + ko] =
                *(const uint4*)(Wqkv_t + (((size_t)(n0 + n)) << 8) + k0 + ko);
        }
        __syncthreads();
        bf16x8 a[4], bb[4];
        #pragma unroll
        for (int mt = 0; mt < 4; ++mt)
            a[mt] = *(const bf16x8*)&A_lds[(mt * 16 + l15) * 32 + quad * 8];
        #pragma unroll
        for (int nt = 0; nt < 4; ++nt)
            bb[nt] = *(const bf16x8*)&B_lds[(w * 64 + nt * 16 + l15) * 32 + quad * 8];
        #pragma unroll
        for (int mt = 0; mt < 4; ++mt)
            #pragma unroll
            for (int nt = 0; nt < 4; ++nt)
                acc[mt][nt] = __builtin_amdgcn_mfma_f32_16x16x32_bf16(
                    a[mt], bb[nt], acc[mt][nt], 0, 0, 0);
        __syncthreads();
    }

    // epilogue: Q,K -> [bh_l][s][64]; V -> [bh_l][64][s]
    #pragma unroll
    for (int nt = 0; nt < 4; ++nt) {
        const int n_g = n0 + w * 64 + nt * 16 + l15;
        const int seg = n_g >> 8;            // 0=Q 1=K 2=V (one seg per block)
        const int within = n_g & 255;
        const int h = within >> 6, d = within & 63;
        const float bias = bqkv_f[n_g];
        const size_t bh = (size_t)(bl * 4 + h);
        #pragma unroll
        for (int mt = 0; mt < 4; ++mt) {
            const int sbase = (m0 & 255) + mt * 16 + quad * 4;
            if (seg == 2) {
                ushort pk[4];
                #pragma unroll
                for (int r = 0; r < 4; ++r) pk[r] = f2bf(acc[mt][nt][r] + bias);
                *(ushort4*)(Vt + (bh * 64 + d) * 256 + sbase) =
                    make_ushort4(pk[0], pk[1], pk[2], pk[3]);
            } else if (seg == 0) {
                #pragma unroll
                for (int r = 0; r < 4; ++r)
                    Qg[(bh * 256 + sbase + r) * 64 + d] =
                        f2bf((acc[mt][nt][r] + bias) * 0.125f);  // fold 1/sqrt(64)
            } else {
                #pragma unroll
                for (int r = 0; r < 4; ++r)
                    Kg[(bh * 256 + sbase + r) * 64 + d] = f2bf(acc[mt][nt][r] + bias);
            }
        }
    }
}

// ---------------------------------------------------------------------------
// Kernel 3: flash attention for one half. Grid 512 = (128 batches x 4 heads).
// 4 waves; wave w owns queries 64w..64w+63. NO barriers (P round-trip is
// per-wave LDS; K/V from global scratch). Scale pre-folded into Q.
// ---------------------------------------------------------------------------
__global__ __launch_bounds__(256, 2) void attn_half_kernel(
    const ushort* __restrict__ Qg, const ushort* __restrict__ Kg,
    const ushort* __restrict__ Vt, int half, ushort* __restrict__ ctx)
{
    __shared__ __attribute__((aligned(16))) ushort Pl[4][64 * 72];  // 36 KB
    const int bh_l = blockIdx.x;
    const int b = half * 128 + (bh_l >> 2), h = bh_l & 3;
    const int tid = threadIdx.x;
    const int w = tid >> 6, l = tid & 63, quad = l >> 4, l15 = l & 15;

    const ushort* Qb = Qg + (size_t)bh_l * 256 * 64;
    const ushort* Kb = Kg + (size_t)bh_l * 256 * 64;
    const ushort* Vb = Vt + (size_t)bh_l * 64 * 256;

    bf16x8 qf[4][2];
    #pragma unroll
    for (int mt = 0; mt < 4; ++mt)
        #pragma unroll
        for (int ks = 0; ks < 2; ++ks) {
            int s = w * 64 + mt * 16 + l15;
            qf[mt][ks] = *(const bf16x8*)(Qb + (size_t)s * 64 + ks * 32 + quad * 8);
        }

    f32x4 O[4][4];
    float m_run[4][4], l_run[4][4];
    #pragma unroll
    for (int mt = 0; mt < 4; ++mt) {
        #pragma unroll
        for (int dt = 0; dt < 4; ++dt) { f32x4 z = {0.f,0.f,0.f,0.f}; O[mt][dt] = z; }
        #pragma unroll
        for (int r = 0; r < 4; ++r) { m_run[mt][r] = -1e30f; l_run[mt][r] = 0.f; }
    }

    for (int c = 0; c < 4; ++c) {
        f32x4 sacc[4][4];
        #pragma unroll
        for (int mt = 0; mt < 4; ++mt)
            #pragma unroll
            for (int nt = 0; nt < 4; ++nt) { f32x4 z = {0.f,0.f,0.f,0.f}; sacc[mt][nt] = z; }
        #pragma unroll
        for (int ks = 0; ks < 2; ++ks) {
            bf16x8 kf[4];
            #pragma unroll
            for (int nt = 0; nt < 4; ++nt) {
                int key = c * 64 + nt * 16 + l15;
                kf[nt] = *(const bf16x8*)(Kb + (size_t)key * 64 + ks * 32 + quad * 8);
            }
            #pragma unroll
            for (int mt = 0; mt < 4; ++mt)
                #pragma unroll
                for (int nt = 0; nt < 4; ++nt)
                    sacc[mt][nt] = __builtin_amdgcn_mfma_f32_16x16x32_bf16(
                        qf[mt][ks], kf[nt], sacc[mt][nt], 0, 0, 0);
        }

        // online softmax (scale folded into Q)
        #pragma unroll
        for (int mt = 0; mt < 4; ++mt) {
            f32x4 mx = sacc[mt][0];
            #pragma unroll
            for (int nt = 1; nt < 4; ++nt)
                #pragma unroll
                for (int r = 0; r < 4; ++r) mx[r] = fmaxf(mx[r], sacc[mt][nt][r]);
            #pragma unroll
            for (int r = 0; r < 4; ++r) {
                float v = mx[r];
                v = fmaxf(v, __shfl_xor(v, 1));
                v = fmaxf(v, __shfl_xor(v, 2));
                v = fmaxf(v, __shfl_xor(v, 4));
                v = fmaxf(v, __shfl_xor(v, 8));
                mx[r] = v;
            }
            float rs[4];
            #pragma unroll
            for (int r = 0; r < 4; ++r) {
                float nm = fmaxf(m_run[mt][r], mx[r]);
                float alpha = __expf(m_run[mt][r] - nm);
                m_run[mt][r] = nm;
                l_run[mt][r] *= alpha;
                float sum = 0.f;
                #pragma unroll
                for (int nt = 0; nt < 4; ++nt) {
                    float p = __expf(sacc[mt][nt][r] - nm);
                    sacc[mt][nt][r] = p;
                    sum += p;
                }
                rs[r] = sum;
                #pragma unroll
                for (int dt = 0; dt < 4; ++dt) O[mt][dt][r] *= alpha;
            }
            #pragma unroll
            for (int r = 0; r < 4; ++r) {
                float v = rs[r];
                v += __shfl_xor(v, 1);
                v += __shfl_xor(v, 2);
                v += __shfl_xor(v, 4);
                v += __shfl_xor(v, 8);
                l_run[mt][r] += v;
            }
            // P (C-layout) -> per-wave LDS (row=query, col=key)
            #pragma unroll
            for (int nt = 0; nt < 4; ++nt)
                #pragma unroll
                for (int r = 0; r < 4; ++r)
                    Pl[w][(mt * 16 + quad * 4 + r) * 72 + nt * 16 + l15] =
                        f2bf(sacc[mt][nt][r]);
        }

        // O += P @ V (per-wave LDS; within-wave ordering suffices, no barrier)
        #pragma unroll
        for (int ks = 0; ks < 2; ++ks) {
            bf16x8 pf[4], vf[4];
            #pragma unroll
            for (int mt = 0; mt < 4; ++mt)
                pf[mt] = *(const bf16x8*)&Pl[w][(mt * 16 + l15) * 72 + ks * 32 + quad * 8];
            #pragma unroll
            for (int dt = 0; dt < 4; ++dt)
                vf[dt] = *(const bf16x8*)(Vb + (size_t)(dt * 16 + l15) * 256 +
                                          c * 64 + ks * 32 + quad * 8);
            #pragma unroll
            for (int mt = 0; mt < 4; ++mt)
                #pragma unroll
                for (int dt = 0; dt < 4; ++dt)
                    O[mt][dt] = __builtin_amdgcn_mfma_f32_16x16x32_bf16(
                        pf[mt], vf[dt], O[mt][dt], 0, 0, 0);
        }
    }

    #pragma unroll
    for (int mt = 0; mt < 4; ++mt) {
        #pragma unroll
        for (int r = 0; r < 4; ++r) {
            float inv = 1.0f / l_run[mt][r];
            const int s = w * 64 + mt * 16 + quad * 4 + r;
            const size_t base = ((size_t)(b * 256 + s)) * 256 + h * 64;
            #pragma unroll
            for (int dt = 0; dt < 4; ++dt)
                ctx[base + dt * 16 + l15] = f2bf(O[mt][dt][r] * inv);
        }
    }
}

// ---------------------------------------------------------------------------
// Kernel 4: out = gsize>1 ? bs + ctx@Wo + bo : bs. Output dtype = input dtype.
// Overwrites d_out (scratch Q/K/Vt regions are dead by now).
// ---------------------------------------------------------------------------
__global__ __launch_bounds__(256, 2) void out_kernel(
    const int* __restrict__ flag,
    const ushort* __restrict__ ctx, const ushort* __restrict__ Wo_t,
    const float* __restrict__ bo_f, const void* __restrict__ bs,
    const int* __restrict__ gsize, void* __restrict__ outv)
{
    __shared__ __attribute__((aligned(16))) ushort A_lds[64 * 32];
    __shared__ __attribute__((aligned(16))) ushort B_lds[256 * 32];

    const int m0 = blockIdx.x * 64;
    const int tid = threadIdx.x;
    const int w = tid >> 6, l = tid & 63, quad = l >> 4, l15 = l & 15;
    const int b = m0 >> 8;
    const bool pass = (gsize[b] <= 1);
    const bool is_f32 = (*flag != 0);

    f32x4 acc[4][4];
    #pragma unroll
    for (int i = 0; i < 4; ++i)
        #pragma unroll
        for (int j = 0; j < 4; ++j) { f32x4 z = {0.f,0.f,0.f,0.f}; acc[i][j] = z; }

    const int arow = tid >> 2, ako = (tid & 3) * 8;
    for (int k0 = 0; k0 < 256; k0 += 32) {
        *(uint4*)&A_lds[arow * 32 + ako] =
            *(const uint4*)(ctx + (((size_t)(m0 + arow)) << 8) + k0 + ako);
        #pragma unroll
        for (int i = 0; i < 4; ++i) {
            int f = tid + i * 256;
            int n = f >> 2, ko = (f & 3) * 8;
            *(uint4*)&B_lds[n * 32 + ko] =
                *(const uint4*)(Wo_t + (((size_t)n) << 8) + k0 + ko);
        }
        __syncthreads();
        bf16x8 a[4], bb[4];
        #pragma unroll
        for (int mt = 0; mt < 4; ++mt)
            a[mt] = *(const bf16x8*)&A_lds[(mt * 16 + l15) * 32 + quad * 8];
        #pragma unroll
        for (int nt = 0; nt < 4; ++nt)
            bb[nt] = *(const bf16x8*)&B_lds[(w * 64 + nt * 16 + l15) * 32 + quad * 8];
        #pragma unroll
        for (int mt = 0; mt < 4; ++mt)
            #pragma unroll
            for (int nt = 0; nt < 4; ++nt)
                acc[mt][nt] = __builtin_amdgcn_mfma_f32_16x16x32_bf16(
                    a[mt], bb[nt], acc[mt][nt], 0, 0, 0);
        __syncthreads();
    }

    #pragma unroll
    for (int nt = 0; nt < 4; ++nt) {
        const int n = w * 64 + nt * 16 + l15;
        const float bias = bo_f[n];
        #pragma unroll
        for (int mt = 0; mt < 4; ++mt)
            #pragma unroll
            for (int r = 0; r < 4; ++r) {
                int token = m0 + mt * 16 + quad * 4 + r;
                size_t idx = (((size_t)token) << 8) + n;
                float base = is_f32 ? ((const float*)bs)[idx]
                                    : bf2f(((const ushort*)bs)[idx]);
                float v = pass ? base : (base + acc[mt][nt][r] + bias);
                if (is_f32) ((float*)outv)[idx] = v;
                else        ((ushort*)outv)[idx] = f2bf(v);
            }
    }
}

// ---------------------------------------------------------------------------
extern "C" void kernel_launch(void* const* d_in, const int* in_sizes, int n_in,
                              void* d_out, int out_size, void* d_ws, size_t ws_size,
                              hipStream_t stream)
{
    int bs_i = -1, obj_i = -1, sc_i = -1;
    int w_i[4] = {2, 3, 4, 5}; int nw = 0;
    int c_i[5] = {1, 6, 7, 8, 9}; int nc = 0;
    for (int i = 0; i < n_in; ++i) {
        int s = in_sizes[i];
        if      (s == 16777216) bs_i = i;
        else if (s == 65536)  { if (nw < 4) w_i[nw] = i; ++nw; }
        else if (s == 12800)    obj_i = i;
        else if (s == 1)        sc_i = i;
        else if (s == 256)    { if (nc < 5) c_i[nc] = i; ++nc; }
    }
    if (bs_i < 0 || obj_i < 0 || sc_i < 0 || nw != 4 || nc != 5) {
        bs_i = 0; obj_i = 10; sc_i = 11;
        w_i[0] = 2; w_i[1] = 3; w_i[2] = 4; w_i[3] = 5;
        c_i[0] = 1; c_i[1] = 6; c_i[2] = 7; c_i[3] = 8; c_i[4] = 9;
    }
    const void* bs    = d_in[bs_i];
    const void* Wq    = d_in[w_i[0]];
    const void* Wk    = d_in[w_i[1]];
    const void* Wv    = d_in[w_i[2]];
    const void* Wo    = d_in[w_i[3]];
    const void* obj   = d_in[obj_i];
    const void* scale = d_in[sc_i];

    // ws: proven-safe footprint (34.5 MB; identical to round-5 green run)
    char* ws = (char*)d_ws;
    int*    flag    = (int*)ws;
    int*    rank    = (int*)(ws + 1024);
    int*    gsize   = (int*)(ws + 2048);
    float*  scale_f = (float*)(ws + 3072);
    float*  bqkv_f  = (float*)(ws + 4096);
    float*  bo_f    = (float*)(ws + 8192);
    ushort* Wqkv_t  = (ushort*)(ws + 16384);
    ushort* Wo_t    = (ushort*)(ws + 16384 + 393216);
    ushort* ctx     = (ushort*)(ws + (1 << 20));      // 32 MB bf16 [token][256]

    // d_out doubles as per-half QKV scratch (48 MB of the 64 MB f32 buffer);
    // dead by the time out_kernel overwrites d_out with the final result.
    ushort* Qg = (ushort*)d_out;            // 16 MB [bh_l][s][64]
    ushort* Kg = Qg + 8388608;              // 16 MB [bh_l][s][64]
    ushort* Vt = Kg + 8388608;              // 16 MB [bh_l][64][s]

    hipLaunchKernelGGL(sniff_kernel, dim3(1), dim3(256), 0, stream,
                       (const unsigned int*)bs, flag);
    hipLaunchKernelGGL(prep_kernel, dim3(257), dim3(256), 0, stream,
                       flag, Wq, Wk, Wv, Wo,
                       d_in[c_i[0]], d_in[c_i[1]], d_in[c_i[2]],
                       d_in[c_i[3]], d_in[c_i[4]], scale,
                       rank, gsize, Wqkv_t, Wo_t, bqkv_f, bo_f, scale_f);
    for (int half = 0; half < 2; ++half) {
        hipLaunchKernelGGL(qkv_half_kernel, dim3(3, 512), dim3(256), 0, stream,
                           flag, bs, obj, scale_f, Wqkv_t, bqkv_f, rank, half,
                           Qg, Kg, Vt);
        hipLaunchKernelGGL(attn_half_kernel, dim3(512), dim3(256), 0, stream,
                           Qg, Kg, Vt, half, ctx);
    }
    hipLaunchKernelGGL(out_kernel, dim3(1024), dim3(256), 0, stream,
                       flag, ctx, Wo_t, bo_f, bs, gsize, d_out);
}